// Round 1
// baseline (322.616 us; speedup 1.0000x reference)
//
#include <hip/hip_runtime.h>
#include <stdint.h>

#define BATCH 256
#define IN_F  1024
#define OUT_F 1024
#define RT    16   // row tiles (IN_F/64)
#define STN   16   // input bit-streams
#define BSN   8    // weight bit-slices
#define BB    16   // batch rows per block
#define OB    16   // output cols per block

// ---------------------------------------------------------------------------
// Prep A: input bit masks. IM[b][r][t] = 64-bit mask, bit k = bit t of the
// 16-bit two's-complement fixed-point value of x[b, r*64+k].
// ---------------------------------------------------------------------------
__global__ void pack_input_bits(const float* __restrict__ x,
                                unsigned long long* __restrict__ IM) {
    int b    = blockIdx.x;
    int wv   = threadIdx.x >> 6;
    int lane = threadIdx.x & 63;
    for (int r = wv; r < RT; r += 4) {
        float xval = x[b * IN_F + r * 64 + lane];
        float xf = rintf(xval * 4096.0f);                 // round half-even
        xf = fminf(fmaxf(xf, -32768.0f), 32767.0f);       // clip
        int xi = (int)xf;
        unsigned xu = (xi < 0) ? (unsigned)(xi + 65536) : (unsigned)xi;
        unsigned long long mine = 0ULL;
        #pragma unroll
        for (int t = 0; t < STN; ++t) {
            unsigned long long m = __ballot((int)((xu >> t) & 1u));
            if (t == lane) mine = m;
        }
        if (lane < STN) IM[(b * RT + r) * STN + lane] = mine;
    }
}

// ---------------------------------------------------------------------------
// Prep B: weight slice bitplanes. For sign sg, output o, row tile r, slice s:
// WM[((sg*OUT_F+o)*RT+r)*BSN+s] = {hi_mask, lo_mask} over the 64 rows k,
// where slice = (w_int >> (14-2s)) & 3 = 2*hi + lo.
// ---------------------------------------------------------------------------
__global__ void pack_weight_masks(const float* __restrict__ w,
                                  ulonglong2* __restrict__ WM) {
    int o    = blockIdx.x;
    int wv   = threadIdx.x >> 6;
    int lane = threadIdx.x & 63;
    for (int r = wv; r < RT; r += 4) {
        float wval = w[o * IN_F + r * 64 + lane];
        float wpf = rintf(fmaxf(wval, 0.0f) * 4096.0f);
        wpf = fminf(fmaxf(wpf, 0.0f), 65535.0f);
        float wnf = rintf(fmaxf(-wval, 0.0f) * 4096.0f);
        wnf = fminf(fmaxf(wnf, 0.0f), 65535.0f);
        unsigned wpi = (unsigned)wpf;
        unsigned wni = (unsigned)wnf;
        #pragma unroll
        for (int s = 0; s < BSN; ++s) {
            unsigned long long hP = __ballot((int)((wpi >> (15 - 2 * s)) & 1u));
            unsigned long long lP = __ballot((int)((wpi >> (14 - 2 * s)) & 1u));
            unsigned long long hN = __ballot((int)((wni >> (15 - 2 * s)) & 1u));
            unsigned long long lN = __ballot((int)((wni >> (14 - 2 * s)) & 1u));
            if (lane == 0) {
                WM[((size_t)(0 * OUT_F + o) * RT + r) * BSN + s] = make_ulonglong2(hP, lP);
                WM[((size_t)(1 * OUT_F + o) * RT + r) * BSN + s] = make_ulonglong2(hN, lN);
            }
        }
    }
}

// ---------------------------------------------------------------------------
// Main: per thread = one (b, o) output. For each row tile r and sign:
//   for t in 16 streams: a[s] = 2*popc(im&hi[s]) + popc(im&lo[s])
//   ADC: qf = rintf(a * 85/64)  (exact fp32 product -> matches ref's a/step
//        with round-half-even, ties at a=32,96,160 included)
//   v = qf * stepf  (bitwise == ref), dig = sum_s v * 4^(7-s) (exact *2^k),
//   accr += dig * (+-2^t)  (exact product), sum over r, pos - neg.
// ---------------------------------------------------------------------------
__global__ __launch_bounds__(256) void cim_mvm(
    const unsigned long long* __restrict__ IM,
    const ulonglong2* __restrict__ WM,
    const float* __restrict__ bias,
    float* __restrict__ out)
{
    __shared__ unsigned long long im_lds[BB][STN + 1];  // +1 pad: bank spread
    const float stepf = 192.0f / 255.0f;
    const float ws_tab[8] = {16384.0f, 4096.0f, 1024.0f, 256.0f,
                             64.0f, 16.0f, 4.0f, 1.0f};
    int tid   = threadIdx.x;
    int b_loc = tid >> 4, o_loc = tid & 15;
    int b0 = blockIdx.y * BB, o0 = blockIdx.x * OB;
    int b = b0 + b_loc, o = o0 + o_loc;

    float accp = 0.0f, accn = 0.0f;

    for (int r = 0; r < RT; ++r) {
        __syncthreads();
        // stage the 16b x 16t input masks for this row tile
        im_lds[tid >> 4][tid & 15] = IM[((size_t)(b0 + (tid >> 4)) * RT + r) * STN + (tid & 15)];
        __syncthreads();

        #pragma unroll
        for (int sg = 0; sg < 2; ++sg) {
            const ulonglong2* wm = WM + ((size_t)(sg * OUT_F + o) * RT + r) * BSN;
            ulonglong2 m[8];
            #pragma unroll
            for (int s = 0; s < 8; ++s) m[s] = wm[s];

            float accr = 0.0f;
            #pragma unroll
            for (int t = 0; t < STN; ++t) {
                unsigned long long im = im_lds[b_loc][t];
                float dig = 0.0f;
                #pragma unroll
                for (int s = 0; s < 8; ++s) {
                    // skip slices that are zero across the whole wave
                    // (contributes exactly 0.0 to dig, matching ref)
                    if (__any((m[s].x | m[s].y) != 0ULL)) {
                        int a = 2 * __popcll(im & m[s].x) + __popcll(im & m[s].y);
                        float qf = rintf((float)a * 1.328125f);   // round(a*85/64), half-even
                        dig = fmaf(qf * stepf, ws_tab[s], dig);   // v*2^k exact product
                    }
                }
                float wt = (t == 15) ? -32768.0f : (float)(1 << t);
                accr = fmaf(dig, wt, accr);                        // exact product
            }
            if (sg == 0) accp += accr; else accn += accr;
        }
    }

    float ov = (accp - accn) * 0x1p-24f;
    float q  = rintf(ov * 4096.0f);
    q = fminf(fmaxf(q, -32768.0f), 32767.0f);
    out[(size_t)b * OUT_F + o] = q * 0x1p-12f + bias[o];
}

// ---------------------------------------------------------------------------
extern "C" void kernel_launch(void* const* d_in, const int* in_sizes, int n_in,
                              void* d_out, int out_size, void* d_ws, size_t ws_size,
                              hipStream_t stream) {
    const float* x    = (const float*)d_in[0];
    const float* w    = (const float*)d_in[1];
    const float* bias = (const float*)d_in[2];
    float* out = (float*)d_out;

    unsigned long long* IM = (unsigned long long*)d_ws;                 // 512 KB
    ulonglong2* WM = (ulonglong2*)((char*)d_ws +
                                   (size_t)BATCH * RT * STN * sizeof(unsigned long long)); // 4 MB

    hipLaunchKernelGGL(pack_input_bits,  dim3(BATCH), dim3(256), 0, stream, x, IM);
    hipLaunchKernelGGL(pack_weight_masks, dim3(OUT_F), dim3(256), 0, stream, w, WM);
    hipLaunchKernelGGL(cim_mvm, dim3(OUT_F / OB, BATCH / BB), dim3(256), 0, stream,
                       IM, WM, bias, out);
}